// Round 1
// baseline (277.013 us; speedup 1.0000x reference)
//
#include <hip/hip_runtime.h>
#include <hip/hip_bf16.h>
#include <math.h>

// Problem constants (fixed by the reference): B=8, S=4096, D=1024, Q=16
#define ROWS_TOTAL 32768
#define DDIM 1024
#define QDIM 16
#define TPB 512
#define ROWS_PER_BLOCK 16
#define NBLOCKS (ROWS_TOTAL / ROWS_PER_BLOCK)  // 2048

// Fused: h = relu(x@W1 + b1); z = cos(h + theta); out = z@W2 + b2
// Thread mapping: qg = t&3 owns q in [4qg,4qg+4); c = t>>2 owns k in [8c,8c+8);
// thread t owns output columns d = 2t, 2t+1. W1/W2 slices register-resident.
__global__ __launch_bounds__(TPB, 4)
void ffq_kernel(const float* __restrict__ x, const float* __restrict__ W1,
                const float* __restrict__ b1, const float* __restrict__ theta,
                const float* __restrict__ W2, const float* __restrict__ b2,
                float* __restrict__ out) {
  const int t    = threadIdx.x;
  const int qg   = t & 3;
  const int c    = t >> 2;
  const int wid  = t >> 6;
  const int lane = t & 63;

  __shared__ __align__(16) float hw[8 * QDIM];  // per-wave partial h[q]
  __shared__ __align__(16) float zs[QDIM];      // z broadcast buffer

  // ---- per-block constant registers (loaded once, reused for 16 rows) ----
  float w1r[8][4];  // W1[8c+j][4qg+i]
  {
    const float* p = W1 + (size_t)(8 * c) * QDIM + 4 * qg;
#pragma unroll
    for (int j = 0; j < 8; ++j) {
      float4 v = *reinterpret_cast<const float4*>(p + (size_t)j * QDIM);
      w1r[j][0] = v.x; w1r[j][1] = v.y; w1r[j][2] = v.z; w1r[j][3] = v.w;
    }
  }
  float w2r[QDIM][2];  // W2[q][2t+i]
#pragma unroll
  for (int q = 0; q < QDIM; ++q) {
    float2 v = *reinterpret_cast<const float2*>(W2 + (size_t)q * DDIM + 2 * t);
    w2r[q][0] = v.x; w2r[q][1] = v.y;
  }
  float2 b2r = *reinterpret_cast<const float2*>(b2 + 2 * t);
  float b1r = 0.f, thr = 0.f;
  if (t < QDIM) { b1r = b1[t]; thr = theta[t]; }

  const int row0 = blockIdx.x * ROWS_PER_BLOCK;

  // x chunk registers: current + prefetch (8 floats each)
  float4 xa, xb, xa_n, xb_n;
  {
    const float* p = x + (size_t)row0 * DDIM + 8 * c;
    xa = *reinterpret_cast<const float4*>(p);
    xb = *reinterpret_cast<const float4*>(p + 4);
  }

  for (int i = 0; i < ROWS_PER_BLOCK; ++i) {
    const int row = row0 + i;

    // mm1: partial h over this thread's 8 k values, 4 q's
    float hp[4] = {0.f, 0.f, 0.f, 0.f};
    {
      const float xv[8] = {xa.x, xa.y, xa.z, xa.w, xb.x, xb.y, xb.z, xb.w};
#pragma unroll
      for (int j = 0; j < 8; ++j)
#pragma unroll
        for (int q = 0; q < 4; ++q)
          hp[q] = fmaf(xv[j], w1r[j][q], hp[q]);
    }

    // software prefetch next row's x (independent of everything below)
    if (i + 1 < ROWS_PER_BLOCK) {
      const float* p = x + (size_t)(row + 1) * DDIM + 8 * c;
      xa_n = *reinterpret_cast<const float4*>(p);
      xb_n = *reinterpret_cast<const float4*>(p + 4);
    }

    // butterfly over the 16 chunks within the wave (lanes sharing qg)
#pragma unroll
    for (int m = 4; m < 64; m <<= 1)
#pragma unroll
      for (int q = 0; q < 4; ++q)
        hp[q] += __shfl_xor(hp[q], m, 64);

    // lanes 0..3 hold the wave sum for qg = lane
    if (lane < 4)
      *reinterpret_cast<float4*>(&hw[wid * QDIM + 4 * lane]) =
          make_float4(hp[0], hp[1], hp[2], hp[3]);
    __syncthreads();

    if (t < QDIM) {
      float s = 0.f;
#pragma unroll
      for (int w = 0; w < 8; ++w) s += hw[w * QDIM + t];
      s = fmaxf(s + b1r, 0.f) + thr;
      zs[t] = __cosf(s);
    }
    __syncthreads();

    // mm2: out[row][2t..2t+1] = zs @ W2 + b2
    float4 z4[4];
#pragma unroll
    for (int j = 0; j < 4; ++j)
      z4[j] = *reinterpret_cast<const float4*>(&zs[4 * j]);
    float o0 = b2r.x, o1 = b2r.y;
#pragma unroll
    for (int j = 0; j < 4; ++j) {
      const float zq[4] = {z4[j].x, z4[j].y, z4[j].z, z4[j].w};
#pragma unroll
      for (int k = 0; k < 4; ++k) {
        o0 = fmaf(zq[k], w2r[4 * j + k][0], o0);
        o1 = fmaf(zq[k], w2r[4 * j + k][1], o1);
      }
    }
    *reinterpret_cast<float2*>(out + (size_t)row * DDIM + 2 * t) =
        make_float2(o0, o1);

    xa = xa_n; xb = xb_n;
  }
}

extern "C" void kernel_launch(void* const* d_in, const int* in_sizes, int n_in,
                              void* d_out, int out_size, void* d_ws, size_t ws_size,
                              hipStream_t stream) {
  const float* x     = (const float*)d_in[0];
  const float* W1    = (const float*)d_in[1];
  const float* b1    = (const float*)d_in[2];
  const float* theta = (const float*)d_in[3];
  const float* W2    = (const float*)d_in[4];
  const float* b2    = (const float*)d_in[5];
  float* out = (float*)d_out;

  ffq_kernel<<<dim3(NBLOCKS), dim3(TPB), 0, stream>>>(x, W1, b1, theta, W2, b2, out);
}

// Round 2
// 255.392 us; speedup vs baseline: 1.0847x; 1.0847x over previous
//
#include <hip/hip_runtime.h>
#include <math.h>

// Problem constants: B=8, S=4096, D=1024, Q=16  -> 32768 rows
#define ROWS_TOTAL 32768
#define DDIM 1024
#define QDIM 16
#define TPB 512
#define RPB 16          // rows per block
#define R 4             // rows per phase
#define NPH (RPB / R)   // 4 phases
#define NBLOCKS (ROWS_TOTAL / RPB)  // 2048

// Fused: h = relu(x@W1 + b1); z = cos(h + theta); out = z@W2 + b2
// Per phase (4 rows): mm1 (reg W1) -> 3-stage butterfly -> hw partials ->
// ONE barrier -> prefetch next x -> mm2(prev phase, zs visible via barrier)
// -> all-lane reduce+cos -> per-wave zs write. 5 barriers/block vs 32 before.
__global__ __launch_bounds__(TPB, 4)
void ffq_kernel(const float* __restrict__ x, const float* __restrict__ W1,
                const float* __restrict__ b1, const float* __restrict__ theta,
                const float* __restrict__ W2, const float* __restrict__ b2,
                float* __restrict__ out) {
  const int t    = threadIdx.x;
  const int lane = t & 63;
  const int wid  = t >> 6;
  const int qg   = t & 3;    // mm1: 4 q's = 4qg..4qg+3
  const int c    = t >> 2;   // mm1: k-chunk of 8 at 8c
  const int q5   = lane & 15;  // reduce/cos: this lane's q
  const int r5   = lane >> 4;  // reduce/cos: this lane's row-in-phase

  __shared__ __align__(16) float hw[2][16][R][QDIM];  // [buf][contrib][r][q]
  __shared__ __align__(16) float zs[8][R][QDIM];      // per-wave z broadcast

  // ---- per-block register-resident weights (block holds W1/W2 exactly once)
  float w1r[8][4];  // W1[8c+j][4qg+i]
  {
    const float* p = W1 + (size_t)(8 * c) * QDIM + 4 * qg;
#pragma unroll
    for (int j = 0; j < 8; ++j) {
      float4 v = *reinterpret_cast<const float4*>(p + (size_t)j * QDIM);
      w1r[j][0] = v.x; w1r[j][1] = v.y; w1r[j][2] = v.z; w1r[j][3] = v.w;
    }
  }
  float w2r[QDIM][2];  // W2[q][2t+i]
#pragma unroll
  for (int q = 0; q < QDIM; ++q) {
    float2 v = *reinterpret_cast<const float2*>(W2 + (size_t)q * DDIM + 2 * t);
    w2r[q][0] = v.x; w2r[q][1] = v.y;
  }
  const float2 b2r = *reinterpret_cast<const float2*>(b2 + 2 * t);
  const float b1q = b1[q5];
  const float thq = theta[q5];

  const int row0 = blockIdx.x * RPB;

  // x registers for the current phase's 4 rows (8 floats each)
  float4 xa[R], xb[R];
  {
    const float* p = x + (size_t)row0 * DDIM + 8 * c;
#pragma unroll
    for (int r = 0; r < R; ++r) {
      xa[r] = *reinterpret_cast<const float4*>(p + (size_t)r * DDIM);
      xb[r] = *reinterpret_cast<const float4*>(p + (size_t)r * DDIM + 4);
    }
  }

  // mm2 helper: consumes zs[wid][*] for rows rowp..rowp+3
  auto mm2_store = [&](int rowp) {
#pragma unroll
    for (int r = 0; r < R; ++r) {
      float o0 = b2r.x, o1 = b2r.y;
#pragma unroll
      for (int jb = 0; jb < 4; ++jb) {
        float4 z = *reinterpret_cast<const float4*>(&zs[wid][r][4 * jb]);
        o0 = fmaf(z.x, w2r[4 * jb + 0][0], o0);
        o1 = fmaf(z.x, w2r[4 * jb + 0][1], o1);
        o0 = fmaf(z.y, w2r[4 * jb + 1][0], o0);
        o1 = fmaf(z.y, w2r[4 * jb + 1][1], o1);
        o0 = fmaf(z.z, w2r[4 * jb + 2][0], o0);
        o1 = fmaf(z.z, w2r[4 * jb + 2][1], o1);
        o0 = fmaf(z.w, w2r[4 * jb + 3][0], o0);
        o1 = fmaf(z.w, w2r[4 * jb + 3][1], o1);
      }
      *reinterpret_cast<float2*>(out + (size_t)(rowp + r) * DDIM + 2 * t) =
          make_float2(o0, o1);
    }
  };

  for (int ph = 0; ph < NPH; ++ph) {
    const int buf = ph & 1;

    // ---- mm1: 4 rows x 4 q partials over this thread's 8 k's
    float hp[R][4];
#pragma unroll
    for (int r = 0; r < R; ++r) {
      const float xv[8] = {xa[r].x, xa[r].y, xa[r].z, xa[r].w,
                           xb[r].x, xb[r].y, xb[r].z, xb[r].w};
      float h0 = 0.f, h1 = 0.f, h2 = 0.f, h3 = 0.f;
#pragma unroll
      for (int j = 0; j < 8; ++j) {
        h0 = fmaf(xv[j], w1r[j][0], h0);
        h1 = fmaf(xv[j], w1r[j][1], h1);
        h2 = fmaf(xv[j], w1r[j][2], h2);
        h3 = fmaf(xv[j], w1r[j][3], h3);
      }
      hp[r][0] = h0; hp[r][1] = h1; hp[r][2] = h2; hp[r][3] = h3;
    }

    // ---- 3-stage butterfly (stays within 32-lane halves -> ds_swizzle)
#pragma unroll
    for (int m = 4; m <= 16; m <<= 1)
#pragma unroll
      for (int r = 0; r < R; ++r)
#pragma unroll
        for (int qq = 0; qq < 4; ++qq)
          hp[r][qq] += __shfl_xor(hp[r][qq], m, 64);

    // holders: lanes {0..3, 32..35} per wave -> 16 contributors per block
    if ((lane & 28) == 0) {
      const int j = wid * 2 + (lane >> 5);
#pragma unroll
      for (int r = 0; r < R; ++r)
        *reinterpret_cast<float4*>(&hw[buf][j][r][4 * qg]) =
            make_float4(hp[r][0], hp[r][1], hp[r][2], hp[r][3]);
    }
    __syncthreads();  // the ONLY barrier in the phase

    // ---- prefetch next phase's x (no barrier between issue and consumption)
    if (ph + 1 < NPH) {
      const float* p = x + (size_t)(row0 + (ph + 1) * R) * DDIM + 8 * c;
#pragma unroll
      for (int r = 0; r < R; ++r) {
        xa[r] = *reinterpret_cast<const float4*>(p + (size_t)r * DDIM);
        xb[r] = *reinterpret_cast<const float4*>(p + (size_t)r * DDIM + 4);
      }
    }

    // ---- mm2 for the PREVIOUS phase (its zs made visible by this barrier)
    if (ph > 0) mm2_store(row0 + (ph - 1) * R);

    // ---- all-lane reduce + bias/relu/theta/cos; per-wave z broadcast
    float s = 0.f;
#pragma unroll
    for (int j = 0; j < 16; ++j) s += hw[buf][j][r5][q5];
    s = fmaxf(s + b1q, 0.f) + thq;
    zs[wid][r5][q5] = __cosf(s);
  }

  __syncthreads();  // make final phase's zs visible
  mm2_store(row0 + (NPH - 1) * R);
}

extern "C" void kernel_launch(void* const* d_in, const int* in_sizes, int n_in,
                              void* d_out, int out_size, void* d_ws, size_t ws_size,
                              hipStream_t stream) {
  const float* x     = (const float*)d_in[0];
  const float* W1    = (const float*)d_in[1];
  const float* b1    = (const float*)d_in[2];
  const float* theta = (const float*)d_in[3];
  const float* W2    = (const float*)d_in[4];
  const float* b2    = (const float*)d_in[5];
  float* out = (float*)d_out;

  ffq_kernel<<<dim3(NBLOCKS), dim3(TPB), 0, stream>>>(x, W1, b1, theta, W2, b2, out);
}